// Round 1
// baseline (577.276 us; speedup 1.0000x reference)
//
#include <hip/hip_runtime.h>

// DeepFilter: out[b,0,t,f<256] = sum_k pr[t+k-4]*cr[k] - pi[t+k-4]*ci[k]
//             out[b,1,t,f<256] = sum_k pi[t+k-4]*cr[k] + pr[t+k-4]*ci[k]
//             out[..., f>=256] = spec[..., f>=256]
// spec  : (B, 2, T, 481) fp32
// coefs : (B, 10, T, 256) fp32  -> cr = coefs[b, k, t, f], ci = coefs[b, 5+k, t, f]

static constexpr int kB  = 8;
static constexpr int kT  = 4096;
static constexpr int kFT = 481;   // total freqs
static constexpr int kNF = 256;   // filtered freqs
static constexpr int kFS = 5;     // frame size (taps)

__global__ __launch_bounds__(256) void df_filter(const float* __restrict__ spec,
                                                 const float* __restrict__ coefs,
                                                 float* __restrict__ out) {
    // t-major indexing so concurrently-resident blocks share df rows in L2:
    // idx = t*(B*64) + b*64 + f4
    int idx = blockIdx.x * 256 + threadIdx.x;
    int f4 = idx & 63;
    int b  = (idx >> 6) & 7;
    int t  = idx >> 9;
    int f  = f4 << 2;

    const float* cr_base = coefs + ((size_t)(b * 10    ) * kT + t) * kNF + f;
    const float* ci_base = coefs + ((size_t)(b * 10 + 5) * kT + t) * kNF + f;
    const float* sr_base = spec + ((size_t)(b * 2    ) * kT) * kFT + f;
    const float* si_base = spec + ((size_t)(b * 2 + 1) * kT) * kFT + f;

    float accR[4] = {0.f, 0.f, 0.f, 0.f};
    float accI[4] = {0.f, 0.f, 0.f, 0.f};

#pragma unroll
    for (int k = 0; k < kFS; ++k) {
        int tk = t + k - (kFS - 1);
        if (tk >= 0) {
            // coefs: f stride-256 rows -> 16B aligned, use float4
            float4 cr = *(const float4*)(cr_base + (size_t)k * kT * kNF);
            float4 ci = *(const float4*)(ci_base + (size_t)k * kT * kNF);
            // spec rows have odd stride 481 -> scalar (coalesced across wave)
            const float* pr = sr_base + (size_t)tk * kFT;
            const float* pi = si_base + (size_t)tk * kFT;
            float crv[4] = {cr.x, cr.y, cr.z, cr.w};
            float civ[4] = {ci.x, ci.y, ci.z, ci.w};
#pragma unroll
            for (int j = 0; j < 4; ++j) {
                float prv = pr[j];
                float piv = pi[j];
                accR[j] = fmaf(prv, crv[j], fmaf(-piv, civ[j], accR[j]));
                accI[j] = fmaf(piv, crv[j], fmaf( prv, civ[j], accI[j]));
            }
        }
    }

    float* outR = out + ((size_t)(b * 2    ) * kT + t) * kFT + f;
    float* outI = out + ((size_t)(b * 2 + 1) * kT + t) * kFT + f;
#pragma unroll
    for (int j = 0; j < 4; ++j) {
        outR[j] = accR[j];
        outI[j] = accI[j];
    }
}

__global__ __launch_bounds__(256) void df_tail(const float* __restrict__ spec,
                                               float* __restrict__ out) {
    // one block per (b, ch, t) row; copy freqs [256, 481)
    int row = blockIdx.x;
    int f   = threadIdx.x;
    if (f < kFT - kNF) {
        size_t off = (size_t)row * kFT + kNF + f;
        out[off] = spec[off];
    }
}

extern "C" void kernel_launch(void* const* d_in, const int* in_sizes, int n_in,
                              void* d_out, int out_size, void* d_ws, size_t ws_size,
                              hipStream_t stream) {
    const float* spec  = (const float*)d_in[0];
    const float* coefs = (const float*)d_in[1];
    float* out = (float*)d_out;

    // filter: B*T*(NF/4) threads = 8*4096*64 = 2,097,152 -> 8192 blocks of 256
    df_filter<<<(kB * kT * (kNF / 4)) / 256, 256, 0, stream>>>(spec, coefs, out);
    // tail: B*2*T rows = 65536 blocks
    df_tail<<<kB * 2 * kT, 256, 0, stream>>>(spec, out);
}